// Round 5
// baseline (286.230 us; speedup 1.0000x reference)
//
#include <hip/hip_runtime.h>
#include <stdint.h>

// AttentionGate, MI355X gfx950 — R5 (= R4 resubmit; R4 bench was an infra
// failure, theory untested): transpose-first pipeline.
//
// R3 post-mortem: three different schedules all ~1.8-2.2 TB/s effective read
// -> pattern-level ceiling from 256 B-granule channel-strided reads.
// This version pays the transpose ONCE with coalesced 1 KB-granule accesses:
//   transpose_kernel: x,g fp32 -> ws bf16 panels [panel][tens][px][ch]
//     (float4-over-px reads = 1 KB/instr; in-register 4x4 transpose;
//      16 B stores L2-merged into full lines by co-located waves).
//   attgate_psi2: stages A-panel from ws with contiguous 16 B/lane loads
//     (1 KB/instr, L3-hot) -> proven STR2=264 LDS layout; K-loop + LN/psi
//     epilogue verbatim from R3.
//   gate_mul: out = psi * x (float4 streaming).  wconv: W -> bf16 fragments.
// Fallback to R3's single-kernel path if ws_size < 68 MB.

typedef __bf16 bf16x8 __attribute__((ext_vector_type(8)));
typedef float f32x4 __attribute__((ext_vector_type(4)));

#define STR2 264          // LDS px-row stride in shorts (528 B; 132 dw = 4 mod 32)
#define LN_EPS 1e-5f

__device__ __forceinline__ uint16_t f2b(float f) {
    union { float f; uint32_t i; } v; v.f = f;
    uint32_t x = v.i;
    return (uint16_t)((x + 0x7FFFu + ((x >> 16) & 1u)) >> 16);  // RNE
}

struct EpiShared {
    float red[3][4][64];   // s, ss, t partials: [value][out-slice][pixel]
    float cpart[8];        // per-wave partials: sumA (0..3), sumB (4..7)
};

union ALds {
    uint16_t a[2][64 * STR2];   // [tensor: 0=x 1=g][px*STR2 + ch]  66 KiB
    EpiShared e;
};

// ---- prepass: W fp32 -> bf16 chunk layout: dst[it*8192 + n*32 + kk] = W[n][it*32+kk]
__global__ void wconv_kernel(const float* __restrict__ Wx, const float* __restrict__ Wg,
                             uint16_t* __restrict__ ox, uint16_t* __restrict__ og) {
    const int i  = blockIdx.x * 256 + threadIdx.x;   // 64 blocks -> 16384
    const int n  = i >> 6;
    const int k4 = (i & 63) * 4;
    const int it = k4 >> 5;
    const int kk = k4 & 31;
    const int dst = it * 8192 + n * 32 + kk;
    const float4 a = *(const float4*)&Wx[n * 256 + k4];
    const float4 b = *(const float4*)&Wg[n * 256 + k4];
    uint2 pa, pb;
    pa.x = (uint32_t)f2b(a.x) | ((uint32_t)f2b(a.y) << 16);
    pa.y = (uint32_t)f2b(a.z) | ((uint32_t)f2b(a.w) << 16);
    pb.x = (uint32_t)f2b(b.x) | ((uint32_t)f2b(b.y) << 16);
    pb.y = (uint32_t)f2b(b.z) | ((uint32_t)f2b(b.w) << 16);
    *(uint2*)&ox[dst] = pa;
    *(uint2*)&og[dst] = pb;
}

// ---- transpose+convert: x,g [b][c][px] fp32 -> ws [panel][tens][px64][ch256] bf16
// Block = 256 px of one image (= 4 consecutive 64-px panels). 1024 threads.
// Reads: float4 over px, 64 lanes x 16 B = 1 KB contiguous per instruction.
// Writes: 16 B (8ch) chunks per px; full 64 B lines assembled in L2 (adjacent
// ch-groups written by co-resident waves of the same block).
__global__ __launch_bounds__(1024) void transpose_kernel(
    const float* __restrict__ x, const float* __restrict__ g,
    uint16_t* __restrict__ ws)
{
    const int t    = threadIdx.x;
    const int lane = t & 63;
    const int wv   = t >> 6;                     // 0..15
    // block covers global px [bid*256, bid*256+256): image b = bid>>4, tile P = bid&15
    const int b = blockIdx.x >> 4;
    const int P = blockIdx.x & 15;
    const size_t rbase = (size_t)b * (256 * 4096) + (size_t)P * 256 + (size_t)lane * 4;
    const int pan0 = blockIdx.x * 4;

    #pragma unroll
    for (int j2 = 0; j2 < 4; ++j2) {
        const int rg   = wv * 4 + j2;            // 0..63
        const int tens = rg >> 5;
        const int cb   = (rg & 31) * 8;          // 8-channel group base
        const float* __restrict__ src = tens ? g : x;

        float4 v[8];
        #pragma unroll
        for (int cc = 0; cc < 8; ++cc)
            v[cc] = *(const float4*)&src[rbase + (size_t)(cb + cc) * 4096];

        const float* vf = (const float*)v;       // vf[cc*4 + j] = ch cb+cc, px 4*lane+j
        #pragma unroll
        for (int j = 0; j < 4; ++j) {
            uint4 w;
            w.x = (uint32_t)f2b(vf[0*4+j]) | ((uint32_t)f2b(vf[1*4+j]) << 16);
            w.y = (uint32_t)f2b(vf[2*4+j]) | ((uint32_t)f2b(vf[3*4+j]) << 16);
            w.z = (uint32_t)f2b(vf[4*4+j]) | ((uint32_t)f2b(vf[5*4+j]) << 16);
            w.w = (uint32_t)f2b(vf[6*4+j]) | ((uint32_t)f2b(vf[7*4+j]) << 16);
            const int px_loc = 4 * lane + j;                 // 0..255
            const int pan    = pan0 + (px_loc >> 6);
            const int px_in  = px_loc & 63;
            const size_t off = (((size_t)pan * 2 + tens) * 64 + px_in) * 256 + cb;
            *(uint4*)&ws[off] = w;
        }
    }
}

// ---- GEMM + LN + psi from transposed ws panels ----
__global__ __launch_bounds__(512, 4) void attgate_psi2(
    const uint16_t* __restrict__ ws,    // [1024][2][64][256] bf16
    const uint16_t* __restrict__ Wxb,   // bf16 chunk layout [8][256][32]
    const uint16_t* __restrict__ Wgb,
    const float* __restrict__ Wpsi,
    const float* __restrict__ gamma,
    const float* __restrict__ beta,
    const float* __restrict__ bxg,
    const float* __restrict__ bpsi,
    float* __restrict__ psi_g)
{
    __shared__ __align__(16) ALds u;

    const int t    = threadIdx.x;
    const int lane = t & 63;
    const int wv   = t >> 6;        // wave 0..7
    const int os   = wv & 3;        // output-channel slice (x64)
    const int ps   = wv >> 2;       // pixel slice (x32), 0..1
    const int ln   = lane & 15;
    const int q    = lane >> 4;     // k-quad 0..3

    const int gp0 = blockIdx.x * 64;             // global pixel base

    // ---- stage 64 KB panel: contiguous 16 B/lane loads (1 KB/instr), L3-hot
    const size_t wsbase = (size_t)blockIdx.x * 32768;   // shorts
    uint16_t* lds0 = &u.a[0][0];
    #pragma unroll
    for (int c = 0; c < 8; ++c) {
        const int o16 = t + c * 512;             // 16B-chunk index, 0..4095
        const uint4 w = *(const uint4*)&ws[wsbase + (size_t)o16 * 8];
        const int row = o16 >> 5;                // [tens*64 + px], 0..127
        const int gch = o16 & 31;                // 16B granule within row
        *(uint4*)&lds0[row * STR2 + gch * 8] = w;   // canonical conflict-free b128
    }

    f32x4 acc[2][4];
    #pragma unroll
    for (int i = 0; i < 2; ++i)
        #pragma unroll
        for (int j = 0; j < 4; ++j)
            acc[i][j] = (f32x4){0.f, 0.f, 0.f, 0.f};

    const int fro = os * 64 + ln;   // W fragment row base offset

    __syncthreads();               // panel staged; the ONLY pre-epilogue barrier

    #pragma unroll
    for (int it = 0; it < 8; ++it) {
        const uint16_t* Wxi = Wxb + it * 8192;
        const uint16_t* Wgi = Wgb + it * 8192;

        bf16x8 bx[4];
        #pragma unroll
        for (int nt = 0; nt < 4; ++nt)
            bx[nt] = *(const bf16x8*)&Wxi[(fro + nt * 16) * 32 + q * 8];

        bf16x8 af[2];
        #pragma unroll
        for (int mt = 0; mt < 2; ++mt)
            af[mt] = *(const bf16x8*)&u.a[0][(ps * 32 + mt * 16 + ln) * STR2 + it * 32 + q * 8];
        #pragma unroll
        for (int mt = 0; mt < 2; ++mt)
            #pragma unroll
            for (int nt = 0; nt < 4; ++nt)
                acc[mt][nt] = __builtin_amdgcn_mfma_f32_16x16x32_bf16(af[mt], bx[nt], acc[mt][nt], 0, 0, 0);

        bf16x8 bg[4];
        #pragma unroll
        for (int nt = 0; nt < 4; ++nt)
            bg[nt] = *(const bf16x8*)&Wgi[(fro + nt * 16) * 32 + q * 8];
        #pragma unroll
        for (int mt = 0; mt < 2; ++mt)
            af[mt] = *(const bf16x8*)&u.a[1][(ps * 32 + mt * 16 + ln) * STR2 + it * 32 + q * 8];
        #pragma unroll
        for (int mt = 0; mt < 2; ++mt)
            #pragma unroll
            for (int nt = 0; nt < 4; ++nt)
                acc[mt][nt] = __builtin_amdgcn_mfma_f32_16x16x32_bf16(af[mt], bg[nt], acc[mt][nt], 0, 0, 0);
    }

    __syncthreads();   // A LDS now reusable as epilogue scratch

    if (t < 256) {
        float a  = Wpsi[t] * gamma[t];
        float bb = Wpsi[t] * beta[t];
        #pragma unroll
        for (int off = 32; off; off >>= 1) {
            a  += __shfl_xor(a, off, 64);
            bb += __shfl_xor(bb, off, 64);
        }
        if (lane == 0) { u.e.cpart[wv] = a; u.e.cpart[4 + wv] = bb; }
    }

    float biasv[4], Ac[4];
    #pragma unroll
    for (int nt = 0; nt < 4; ++nt) {
        const int o = os * 64 + nt * 16 + ln;
        biasv[nt] = bxg[o];
        Ac[nt]    = Wpsi[o] * gamma[o];
    }
    __syncthreads();
    const float sumA = u.e.cpart[0] + u.e.cpart[1] + u.e.cpart[2] + u.e.cpart[3];
    const float sumB = u.e.cpart[4] + u.e.cpart[5] + u.e.cpart[6] + u.e.cpart[7];

    #pragma unroll
    for (int mt = 0; mt < 2; ++mt) {
        #pragma unroll
        for (int r = 0; r < 4; ++r) {
            float s = 0.f, ss = 0.f, tt = 0.f;
            #pragma unroll
            for (int nt = 0; nt < 4; ++nt) {
                float v = acc[mt][nt][r] + biasv[nt];
                v = fmaxf(v, 0.f);               // relu
                s += v; ss += v * v; tt += Ac[nt] * v;
            }
            #pragma unroll
            for (int off = 1; off < 16; off <<= 1) {
                s  += __shfl_xor(s,  off, 64);
                ss += __shfl_xor(ss, off, 64);
                tt += __shfl_xor(tt, off, 64);
            }
            if (ln == 0) {
                const int pix = ps * 32 + mt * 16 + q * 4 + r;
                u.e.red[0][os][pix] = s;
                u.e.red[1][os][pix] = ss;
                u.e.red[2][os][pix] = tt;
            }
        }
    }
    __syncthreads();

    if (t < 64) {
        const float s  = u.e.red[0][0][t] + u.e.red[0][1][t] + u.e.red[0][2][t] + u.e.red[0][3][t];
        const float ss = u.e.red[1][0][t] + u.e.red[1][1][t] + u.e.red[1][2][t] + u.e.red[1][3][t];
        const float tt = u.e.red[2][0][t] + u.e.red[2][1][t] + u.e.red[2][2][t] + u.e.red[2][3][t];
        const float mu   = s * (1.f / 256.f);
        const float var  = ss * (1.f / 256.f) - mu * mu;
        const float rstd = rsqrtf(var + LN_EPS);
        const float z    = rstd * (tt - mu * sumA) + sumB + bpsi[0];
        psi_g[gp0 + t] = 1.f / (1.f + __expf(-z));
    }
}

// ---- R3 fallback (used if ws_size too small): GEMM staged from x,g directly ----
__global__ __launch_bounds__(512, 4) void attgate_psi_fb(
    const float* __restrict__ x,
    const float* __restrict__ g,
    const uint16_t* __restrict__ Wxb,
    const uint16_t* __restrict__ Wgb,
    const float* __restrict__ Wpsi,
    const float* __restrict__ gamma,
    const float* __restrict__ beta,
    const float* __restrict__ bxg,
    const float* __restrict__ bpsi,
    float* __restrict__ psi_g)
{
    __shared__ __align__(16) ALds u;

    const int t    = threadIdx.x;
    const int lane = t & 63;
    const int wv   = t >> 6;
    const int os   = wv & 3;
    const int ps   = wv >> 2;
    const int ln   = lane & 15;
    const int q    = lane >> 4;

    const int gp0  = blockIdx.x * 64;
    const int b    = gp0 >> 12;
    const int pix0 = gp0 & 4095;
    const size_t xbase = (size_t)b * (256 * 4096) + pix0;

    const int at  = t & 255;
    const int px  = at & 63;
    const int cg  = at >> 6;
    const int c0  = cg * 8;
    const float* Asrc = (t < 256) ? x : g;
    const int tens    = (t < 256) ? 0 : 1;

    float av[64];
    #pragma unroll
    for (int it = 0; it < 8; ++it)
        #pragma unroll
        for (int c = 0; c < 8; ++c)
            av[it * 8 + c] = Asrc[xbase + (size_t)(it * 32 + c0 + c) * 4096 + px];

    uint16_t* dstrow = &u.a[tens][px * STR2];
    #pragma unroll
    for (int it = 0; it < 8; ++it) {
        uint4 w;
        w.x = (uint32_t)f2b(av[it*8+0]) | ((uint32_t)f2b(av[it*8+1]) << 16);
        w.y = (uint32_t)f2b(av[it*8+2]) | ((uint32_t)f2b(av[it*8+3]) << 16);
        w.z = (uint32_t)f2b(av[it*8+4]) | ((uint32_t)f2b(av[it*8+5]) << 16);
        w.w = (uint32_t)f2b(av[it*8+6]) | ((uint32_t)f2b(av[it*8+7]) << 16);
        *(uint4*)&dstrow[it * 32 + c0] = w;
    }

    f32x4 acc[2][4];
    #pragma unroll
    for (int i = 0; i < 2; ++i)
        #pragma unroll
        for (int j = 0; j < 4; ++j)
            acc[i][j] = (f32x4){0.f, 0.f, 0.f, 0.f};

    const int fro = os * 64 + ln;
    __syncthreads();

    #pragma unroll
    for (int it = 0; it < 8; ++it) {
        const uint16_t* Wxi = Wxb + it * 8192;
        const uint16_t* Wgi = Wgb + it * 8192;
        bf16x8 bx[4];
        #pragma unroll
        for (int nt = 0; nt < 4; ++nt)
            bx[nt] = *(const bf16x8*)&Wxi[(fro + nt * 16) * 32 + q * 8];
        bf16x8 af[2];
        #pragma unroll
        for (int mt = 0; mt < 2; ++mt)
            af[mt] = *(const bf16x8*)&u.a[0][(ps * 32 + mt * 16 + ln) * STR2 + it * 32 + q * 8];
        #pragma unroll
        for (int mt = 0; mt < 2; ++mt)
            #pragma unroll
            for (int nt = 0; nt < 4; ++nt)
                acc[mt][nt] = __builtin_amdgcn_mfma_f32_16x16x32_bf16(af[mt], bx[nt], acc[mt][nt], 0, 0, 0);
        bf16x8 bg[4];
        #pragma unroll
        for (int nt = 0; nt < 4; ++nt)
            bg[nt] = *(const bf16x8*)&Wgi[(fro + nt * 16) * 32 + q * 8];
        #pragma unroll
        for (int mt = 0; mt < 2; ++mt)
            af[mt] = *(const bf16x8*)&u.a[1][(ps * 32 + mt * 16 + ln) * STR2 + it * 32 + q * 8];
        #pragma unroll
        for (int mt = 0; mt < 2; ++mt)
            #pragma unroll
            for (int nt = 0; nt < 4; ++nt)
                acc[mt][nt] = __builtin_amdgcn_mfma_f32_16x16x32_bf16(af[mt], bg[nt], acc[mt][nt], 0, 0, 0);
    }

    __syncthreads();

    if (t < 256) {
        float a  = Wpsi[t] * gamma[t];
        float bb = Wpsi[t] * beta[t];
        #pragma unroll
        for (int off = 32; off; off >>= 1) {
            a  += __shfl_xor(a, off, 64);
            bb += __shfl_xor(bb, off, 64);
        }
        if (lane == 0) { u.e.cpart[wv] = a; u.e.cpart[4 + wv] = bb; }
    }
    float biasv[4], Ac[4];
    #pragma unroll
    for (int nt = 0; nt < 4; ++nt) {
        const int o = os * 64 + nt * 16 + ln;
        biasv[nt] = bxg[o];
        Ac[nt]    = Wpsi[o] * gamma[o];
    }
    __syncthreads();
    const float sumA = u.e.cpart[0] + u.e.cpart[1] + u.e.cpart[2] + u.e.cpart[3];
    const float sumB = u.e.cpart[4] + u.e.cpart[5] + u.e.cpart[6] + u.e.cpart[7];

    #pragma unroll
    for (int mt = 0; mt < 2; ++mt) {
        #pragma unroll
        for (int r = 0; r < 4; ++r) {
            float s = 0.f, ss = 0.f, tt = 0.f;
            #pragma unroll
            for (int nt = 0; nt < 4; ++nt) {
                float v = acc[mt][nt][r] + biasv[nt];
                v = fmaxf(v, 0.f);
                s += v; ss += v * v; tt += Ac[nt] * v;
            }
            #pragma unroll
            for (int off = 1; off < 16; off <<= 1) {
                s  += __shfl_xor(s,  off, 64);
                ss += __shfl_xor(ss, off, 64);
                tt += __shfl_xor(tt, off, 64);
            }
            if (ln == 0) {
                const int pix = ps * 32 + mt * 16 + q * 4 + r;
                u.e.red[0][os][pix] = s;
                u.e.red[1][os][pix] = ss;
                u.e.red[2][os][pix] = tt;
            }
        }
    }
    __syncthreads();

    if (t < 64) {
        const float s  = u.e.red[0][0][t] + u.e.red[0][1][t] + u.e.red[0][2][t] + u.e.red[0][3][t];
        const float ss = u.e.red[1][0][t] + u.e.red[1][1][t] + u.e.red[1][2][t] + u.e.red[1][3][t];
        const float tt = u.e.red[2][0][t] + u.e.red[2][1][t] + u.e.red[2][2][t] + u.e.red[2][3][t];
        const float mu   = s * (1.f / 256.f);
        const float var  = ss * (1.f / 256.f) - mu * mu;
        const float rstd = rsqrtf(var + LN_EPS);
        const float z    = rstd * (tt - mu * sumA) + sumB + bpsi[0];
        psi_g[gp0 + t] = 1.f / (1.f + __expf(-z));
    }
}

// ---- out = psi * x, pure streaming ----
__global__ __launch_bounds__(256) void gate_mul(
    const float* __restrict__ x,
    const float* __restrict__ psi,
    float* __restrict__ out)
{
    const float4* __restrict__ x4  = (const float4*)x;
    float4* __restrict__ o4        = (float4*)out;
    int i = blockIdx.x * 256 + threadIdx.x;
    #pragma unroll 1
    for (; i < 4194304; i += 524288) {          // 16 images * 256 ch * 1024 f4
        const int b   = i >> 18;                // 262144 f4 per image
        const int rem = i & 262143;
        const int p4  = rem & 1023;             // f4 index within channel row
        const float4 pv = *(const float4*)&psi[(b << 12) + (p4 << 2)];
        const float4 xv = x4[i];
        float4 o;
        o.x = xv.x * pv.x; o.y = xv.y * pv.y; o.z = xv.z * pv.z; o.w = xv.w * pv.w;
        o4[i] = o;
    }
}

extern "C" void kernel_launch(void* const* d_in, const int* in_sizes, int n_in,
                              void* d_out, int out_size, void* d_ws, size_t ws_size,
                              hipStream_t stream) {
    const float* x    = (const float*)d_in[0];
    const float* g    = (const float*)d_in[1];
    const float* Wx   = (const float*)d_in[2];
    const float* Wg   = (const float*)d_in[3];
    const float* Wpsi = (const float*)d_in[4];
    const float* gam  = (const float*)d_in[5];
    const float* bet  = (const float*)d_in[6];
    const float* bxg  = (const float*)d_in[7];
    const float* bpsi = (const float*)d_in[8];
    float* out        = (float*)d_out;

    uint16_t* Wxb = (uint16_t*)d_ws;                       // 131072 B
    uint16_t* Wgb = (uint16_t*)((char*)d_ws + 131072);     // 131072 B
    float*    psi = (float*)((char*)d_ws + 262144);        // 262144 B
    uint16_t* wsT = (uint16_t*)((char*)d_ws + 524288);     // 67108864 B

    const size_t need = 524288 + 67108864;

    wconv_kernel<<<dim3(64), dim3(256), 0, stream>>>(Wx, Wg, Wxb, Wgb);
    if (ws_size >= need) {
        transpose_kernel<<<dim3(256), dim3(1024), 0, stream>>>(x, g, wsT);
        attgate_psi2<<<dim3(1024), dim3(512), 0, stream>>>(
            wsT, Wxb, Wgb, Wpsi, gam, bet, bxg, bpsi, psi);
    } else {
        attgate_psi_fb<<<dim3(1024), dim3(512), 0, stream>>>(
            x, g, Wxb, Wgb, Wpsi, gam, bet, bxg, bpsi, psi);
    }
    gate_mul<<<dim3(2048), dim3(256), 0, stream>>>(x, psi, out);
}

// Round 6
// 213.705 us; speedup vs baseline: 1.3394x; 1.3394x over previous
//
#include <hip/hip_runtime.h>
#include <stdint.h>

// AttentionGate, MI355X gfx950 — R6: fused R1 frame + true-1KB-granule gather.
//
// Model after R0-R5: gather-shaped reads cap ~2.2 TB/s, copy-shaped ~5 TB/s;
// R1 fused (85 us) = gather 128 MB @2.2 + stream 128 MB @5. Only untested
// gather variable: per-instruction granule (R1 staged 4 B/lane = 256 B/instr).
// R6 staging: float4/lane over px -> 64 lanes x 16 B = 1 KB contiguous per
// instruction. Thread = 4ch x 4px block, in-register transpose during bf16
// pack, 4x ds_write_b64 with 2-bit XOR swizzle byte^=((px>>3)&3)<<4
// (bijective within each 80 B row's 64 used bytes; preserves alignment;
// fragment b128 reads apply the same swizzle, ~2-way = free; writes ~8-way
// on 4 instrs/thread/iter = negligible). MFMA schedule, acc[4][4], double
// buffer, prefetch, LN/psi epilogue, f4 out-streaming: verbatim R1.
// 2 dispatches total (wconv prepass + fused kernel).

typedef __bf16 bf16x8 __attribute__((ext_vector_type(8)));
typedef float f32x4 __attribute__((ext_vector_type(4)));

#define STR 40            // LDS row stride in shorts (80 B/row; 64 B used + pad)
#define LN_EPS 1e-5f

__device__ __forceinline__ uint16_t f2b(float f) {
    union { float f; uint32_t i; } v; v.f = f;
    uint32_t x = v.i;
    return (uint16_t)((x + 0x7FFFu + ((x >> 16) & 1u)) >> 16);  // RNE
}

__device__ __forceinline__ int swz(int px) { return ((px >> 3) & 3) << 4; }

struct EpiShared {
    float red[3][4][256];  // s, ss, t partials: [value][out-slice][pixel]
    float psi[256];
    float cpart[8];        // per-wave partials: sumA (0..3), sumB (4..7)
};

union ALds {
    uint16_t a[2][2][256 * STR];  // [buf][tensor: 0=x 1=g][px*STR + ch]  80 KiB
    EpiShared e;
};

// ---- prepass: W fp32 -> bf16 chunk layout: dst[it*8192 + n*32 + kk] = W[n][it*32+kk]
__global__ void wconv_kernel(const float* __restrict__ Wx, const float* __restrict__ Wg,
                             uint16_t* __restrict__ ox, uint16_t* __restrict__ og) {
    const int i  = blockIdx.x * 256 + threadIdx.x;   // 64 blocks -> 16384
    const int n  = i >> 6;
    const int k4 = (i & 63) * 4;
    const int it = k4 >> 5;
    const int kk = k4 & 31;
    const int dst = it * 8192 + n * 32 + kk;
    const float4 a = *(const float4*)&Wx[n * 256 + k4];
    const float4 b = *(const float4*)&Wg[n * 256 + k4];
    uint2 pa, pb;
    pa.x = (uint32_t)f2b(a.x) | ((uint32_t)f2b(a.y) << 16);
    pa.y = (uint32_t)f2b(a.z) | ((uint32_t)f2b(a.w) << 16);
    pb.x = (uint32_t)f2b(b.x) | ((uint32_t)f2b(b.y) << 16);
    pb.y = (uint32_t)f2b(b.z) | ((uint32_t)f2b(b.w) << 16);
    *(uint2*)&ox[dst] = pa;
    *(uint2*)&og[dst] = pb;
}

// Staging thread role: wave w (0..15): tensor = w>>3, channels ch0=4*(w&7)..+3
// of the current 32-ch K-slice; lane l: pixels 4l..4l+3.
// Loads: 4x float4 over px -> each wave-instr = 1 KB contiguous.
__device__ __forceinline__ void stage_load4(float4 av[4], const float* __restrict__ src,
                                            size_t base, int ch0, int l) {
    #pragma unroll
    for (int j2 = 0; j2 < 4; ++j2)
        av[j2] = *(const float4*)&src[base + (size_t)(ch0 + j2) * 4096 + 4 * l];
}

// In-register 4x4 transpose + bf16 pack; 4x ds_write_b64 (swizzled).
__device__ __forceinline__ void stage_store4(const float4 av[4], char* tile,
                                             int w7, int l) {
    const float* vf = (const float*)av;   // vf[j2*4 + j] = (ch0+j2, px 4l+j)
    #pragma unroll
    for (int j = 0; j < 4; ++j) {
        const int px = 4 * l + j;
        uint2 d;
        d.x = (uint32_t)f2b(vf[0 * 4 + j]) | ((uint32_t)f2b(vf[1 * 4 + j]) << 16);
        d.y = (uint32_t)f2b(vf[2 * 4 + j]) | ((uint32_t)f2b(vf[3 * 4 + j]) << 16);
        const int byte = (px * (STR * 2) + 8 * w7) ^ swz(px);
        *(uint2*)(tile + byte) = d;
    }
}

__global__ __launch_bounds__(1024) void attgate_kernel(
    const float* __restrict__ x,
    const float* __restrict__ g,
    const uint16_t* __restrict__ Wxb,   // bf16 chunk layout [8][256][32]
    const uint16_t* __restrict__ Wgb,
    const float* __restrict__ Wpsi,
    const float* __restrict__ gamma,
    const float* __restrict__ beta,
    const float* __restrict__ bxg,
    const float* __restrict__ bpsi,
    float* __restrict__ out)
{
    __shared__ __align__(16) ALds u;

    const int t    = threadIdx.x;
    const int lane = t & 63;
    const int wv   = t >> 6;        // wave 0..15
    const int os   = wv & 3;        // output-channel slice (x64)
    const int ps   = wv >> 2;       // pixel slice (x64)
    const int ln   = lane & 15;     // tile row/col index
    const int q    = lane >> 4;     // quad 0..3 (k-quad)

    const int gp0  = blockIdx.x * 256;           // global pixel base
    const int b    = gp0 >> 12;                  // batch (4096 px per image)
    const int pix0 = gp0 & 4095;
    const size_t xbase = (size_t)b * (256 * 4096) + pix0;  // + c*4096 + p

    f32x4 acc[4][4];
    #pragma unroll
    for (int i = 0; i < 4; ++i)
        #pragma unroll
        for (int j = 0; j < 4; ++j)
            acc[i][j] = (f32x4){0.f, 0.f, 0.f, 0.f};

    // ---- staging role (see stage_load4): wave -> (tensor, 4-ch group)
    const int w7   = wv & 7;
    const int ch0  = 4 * w7;        // within current 32-ch slice
    const float* Asrc = (wv < 8) ? x : g;
    const int tens    = (wv < 8) ? 0 : 1;

    float4 av[4];
    stage_load4(av, Asrc, xbase, ch0, lane);             // it = 0
    stage_store4(av, (char*)&u.a[0][tens][0], w7, lane);

    const int fro = os * 64 + ln;   // W fragment row base offset

    for (int it = 0; it < 8; ++it) {
        __syncthreads();            // buf[it&1] ready; prior reads drained
        const int cur = it & 1;
        const uint16_t* Wxi = Wxb + it * 8192;
        const uint16_t* Wgi = Wgb + it * 8192;

        // B fragments for Wx (global, L2-hot, coalesced)
        bf16x8 bx[4];
        #pragma unroll
        for (int nt = 0; nt < 4; ++nt)
            bx[nt] = *(const bf16x8*)&Wxi[(fro + nt * 16) * 32 + q * 8];

        // prefetch A for it+1 (4 float4; first use after MFMA phase)
        if (it < 7)
            stage_load4(av, Asrc, xbase + (size_t)((it + 1) * 32) * 4096, ch0, lane);

        // A fragments (x) from LDS (swizzled b128) + MFMA x
        bf16x8 af[4];
        #pragma unroll
        for (int mt = 0; mt < 4; ++mt) {
            const int px = ps * 64 + mt * 16 + ln;
            af[mt] = *(const bf16x8*)((const char*)&u.a[cur][0][0] +
                                      ((px * (STR * 2) + q * 16) ^ swz(px)));
        }
        #pragma unroll
        for (int mt = 0; mt < 4; ++mt)
            #pragma unroll
            for (int nt = 0; nt < 4; ++nt)
                acc[mt][nt] = __builtin_amdgcn_mfma_f32_16x16x32_bf16(af[mt], bx[nt], acc[mt][nt], 0, 0, 0);

        // B fragments for Wg + A fragments (g) + MFMA g
        bf16x8 bg[4];
        #pragma unroll
        for (int nt = 0; nt < 4; ++nt)
            bg[nt] = *(const bf16x8*)&Wgi[(fro + nt * 16) * 32 + q * 8];
        #pragma unroll
        for (int mt = 0; mt < 4; ++mt) {
            const int px = ps * 64 + mt * 16 + ln;
            af[mt] = *(const bf16x8*)((const char*)&u.a[cur][1][0] +
                                      ((px * (STR * 2) + q * 16) ^ swz(px)));
        }
        #pragma unroll
        for (int mt = 0; mt < 4; ++mt)
            #pragma unroll
            for (int nt = 0; nt < 4; ++nt)
                acc[mt][nt] = __builtin_amdgcn_mfma_f32_16x16x32_bf16(af[mt], bg[nt], acc[mt][nt], 0, 0, 0);

        // store prefetched A -> other buffer (waits on the it+1 loads here)
        if (it < 7)
            stage_store4(av, (char*)&u.a[cur ^ 1][tens][0], w7, lane);
    }

    __syncthreads();   // A LDS now reusable as epilogue scratch

    // ---- block-wide constants: sumA = sum(Wpsi*gamma), sumB = sum(Wpsi*beta) ----
    if (t < 256) {
        float a  = Wpsi[t] * gamma[t];
        float bb = Wpsi[t] * beta[t];
        #pragma unroll
        for (int off = 32; off; off >>= 1) {
            a  += __shfl_xor(a, off, 64);
            bb += __shfl_xor(bb, off, 64);
        }
        if (lane == 0) { u.e.cpart[wv] = a; u.e.cpart[4 + wv] = bb; }
    }

    // per-lane channel constants (channel o = os*64 + nt*16 + ln)
    float biasv[4], Ac[4];
    #pragma unroll
    for (int nt = 0; nt < 4; ++nt) {
        const int o = os * 64 + nt * 16 + ln;
        biasv[nt] = bxg[o];
        Ac[nt]    = Wpsi[o] * gamma[o];
    }
    __syncthreads();
    const float sumA = u.e.cpart[0] + u.e.cpart[1] + u.e.cpart[2] + u.e.cpart[3];
    const float sumB = u.e.cpart[4] + u.e.cpart[5] + u.e.cpart[6] + u.e.cpart[7];

    // ---- per-pixel reductions: s, ss, t over this wave's 64 channels ----
    #pragma unroll
    for (int mt = 0; mt < 4; ++mt) {
        #pragma unroll
        for (int r = 0; r < 4; ++r) {
            float s = 0.f, ss = 0.f, tt = 0.f;
            #pragma unroll
            for (int nt = 0; nt < 4; ++nt) {
                float v = acc[mt][nt][r] + biasv[nt];
                v = fmaxf(v, 0.f);               // relu
                s += v; ss += v * v; tt += Ac[nt] * v;
            }
            #pragma unroll
            for (int off = 1; off < 16; off <<= 1) {   // reduce 16 lanes (n dim)
                s  += __shfl_xor(s,  off, 64);
                ss += __shfl_xor(ss, off, 64);
                tt += __shfl_xor(tt, off, 64);
            }
            if (ln == 0) {
                const int pix = ps * 64 + mt * 16 + q * 4 + r;   // C/D row = q*4 + reg
                u.e.red[0][os][pix] = s;
                u.e.red[1][os][pix] = ss;
                u.e.red[2][os][pix] = tt;
            }
        }
    }
    __syncthreads();

    // ---- LN + psi dot + sigmoid (one thread per pixel) ----
    if (t < 256) {
        const float s  = u.e.red[0][0][t] + u.e.red[0][1][t] + u.e.red[0][2][t] + u.e.red[0][3][t];
        const float ss = u.e.red[1][0][t] + u.e.red[1][1][t] + u.e.red[1][2][t] + u.e.red[1][3][t];
        const float tt = u.e.red[2][0][t] + u.e.red[2][1][t] + u.e.red[2][2][t] + u.e.red[2][3][t];
        const float mu   = s * (1.f / 256.f);
        const float var  = ss * (1.f / 256.f) - mu * mu;
        const float rstd = rsqrtf(var + LN_EPS);
        const float z    = rstd * (tt - mu * sumA) + sumB + bpsi[0];
        u.e.psi[t] = 1.f / (1.f + __expf(-z));
    }
    __syncthreads();

    // ---- out[c][p] = psi[p] * x[c][p]; one wave = one 1 KB channel row per pass ----
    const int pc = (t & 63) * 4;        // lanes cover px 0..255 contiguously
    const float4 pv = *(const float4*)&u.e.psi[pc];
    const int crow = t >> 6;            // 0..15
    #pragma unroll
    for (int pass = 0; pass < 16; ++pass) {
        const int c = pass * 16 + crow;
        const size_t off = xbase + (size_t)c * 4096 + pc;
        const float4 d = *(const float4*)&x[off];
        float4 o;
        o.x = d.x * pv.x; o.y = d.y * pv.y; o.z = d.z * pv.z; o.w = d.w * pv.w;
        *(float4*)&out[off] = o;
    }
}

extern "C" void kernel_launch(void* const* d_in, const int* in_sizes, int n_in,
                              void* d_out, int out_size, void* d_ws, size_t ws_size,
                              hipStream_t stream) {
    const float* x    = (const float*)d_in[0];
    const float* g    = (const float*)d_in[1];
    const float* Wx   = (const float*)d_in[2];
    const float* Wg   = (const float*)d_in[3];
    const float* Wpsi = (const float*)d_in[4];
    const float* gam  = (const float*)d_in[5];
    const float* bet  = (const float*)d_in[6];
    const float* bxg  = (const float*)d_in[7];
    const float* bpsi = (const float*)d_in[8];
    float* out        = (float*)d_out;

    uint16_t* Wxb = (uint16_t*)d_ws;                 // 131072 B
    uint16_t* Wgb = (uint16_t*)((char*)d_ws + 131072);

    wconv_kernel<<<dim3(64), dim3(256), 0, stream>>>(Wx, Wg, Wxb, Wgb);
    attgate_kernel<<<dim3(256), dim3(1024), 0, stream>>>(
        x, g, Wxb, Wgb, Wpsi, gam, bet, bxg, bpsi, out);
}